// Round 6
// baseline (3700.510 us; speedup 1.0000x reference)
//
#include <hip/hip_runtime.h>
#include <stdint.h>

// Problem constants: B=2048, S=512, F=64, H=256
#define SEQ   512
#define FD    64
#define HD    256
#define ZSTR  324            // bf16 elems per Z row; 162 words % 8 == 2 -> 8/bank floor on b128
#define CSTR  260            // 130 words % 8 == 2

// Weight layout in d_ws (prep kernel writes, main kernel reads):
// 128 gate half-columns (hc): hc = (wave w, idx 0..15), idx -> (s=2w+(idx>>3), nt=(idx>>1)&3, h=idx&1).
// Each hc = 5 chunks of K=32; chunk = 64 lanes x 16B in exact B-fragment order:
//   lane l holds W[n = nt*256+s*16+(l&15)][k = h*160 + c*32 + (l>>4)*8 + e], e=0..7.
// Classes per wave: w<4: idx<4 REG, 4..6 LDS, 7..15 STREAM(9); w>=4: idx<6 REG, 6..8 LDS, 9..15 STREAM(7).
// Slots: REG 0..39, LDS 40..63, STREAM 64..127. Dense W at WS_DENSE_ELEM (4 cols x 8 chunks).
#define HC_ELEMS 2560        // 5120 bytes
#define WS_DENSE_ELEM (128 * HC_ELEMS)

typedef __attribute__((ext_vector_type(8))) __bf16 bf16x8;
typedef __attribute__((ext_vector_type(4))) float  f32x4;

__device__ __forceinline__ int hc_slot(int w, int idx) {
    const int R = (w < 4) ? 4 : 6;
    if (idx < R)     return (w < 4 ? w * 4 : 16 + (w - 4) * 6) + idx;
    if (idx < R + 3) return 40 + w * 3 + (idx - R);
    return 64 + (w < 4 ? w * 9 : 36 + (w - 4) * 7) + (idx - R - 3);
}

__device__ __forceinline__ float sigm(float x) {
    return __builtin_amdgcn_rcpf(1.0f + __expf(-x));
}
__device__ __forceinline__ float tanh_(float x) {
    return 2.0f * __builtin_amdgcn_rcpf(1.0f + __expf(-2.0f * x)) - 1.0f;
}

// ---------------- prep: fp32 weights -> bf16 fragments in ws ----------------
__global__ __launch_bounds__(64) void prep_weights(
    const float* __restrict__ W_ih, const float* __restrict__ W_hh,
    const float* __restrict__ W_dense, __bf16* __restrict__ wsb)
{
    const int b = blockIdx.x, l = threadIdx.x, lr = l & 15, lg = l >> 4;
    if (b < 128) {
        const int w = b >> 4, idx = b & 15;
        const int s = 2 * w + (idx >> 3), nt = (idx >> 1) & 3, h = idx & 1;
        const int n = nt * 256 + s * 16 + lr;
        const int slot = hc_slot(w, idx);
        for (int c = 0; c < 5; ++c) {
            const int k0 = h * 160 + c * 32 + lg * 8;
            const float* src = (k0 < 64) ? (W_ih + n * 64 + k0)
                                         : (W_hh + n * 256 + (k0 - 64));
            bf16x8 v;
            for (int e = 0; e < 8; ++e) v[e] = (__bf16)src[e];
            *(bf16x8*)(wsb + (size_t)slot * HC_ELEMS + c * 512 + l * 8) = v;
        }
    } else {
        const int d = b - 128;
        const int f = d * 16 + lr;
        for (int c = 0; c < 8; ++c) {
            const float* src = W_dense + f * 256 + c * 32 + lg * 8;
            bf16x8 v;
            for (int e = 0; e < 8; ++e) v[e] = (__bf16)src[e];
            *(bf16x8*)(wsb + WS_DENSE_ELEM + d * 4096 + c * 512 + l * 8) = v;
        }
    }
}

// ---------------- main persistent LSTM kernel ----------------
// 128 blocks x 512 threads (8 waves, 2/SIMD). Unified reg budget at 2 waves/EU = 256/wave,
// split by the backend into ~128 arch VGPR + ~128 AGPR (R3-R5 evidence: VGPR_Count pinned
// at 128 while weights remat'ed from L2 every step). Fix: pin the resident weight chunks
// into the AGPR half via empty inline-asm "+a" constraints — MFMA reads B from AGPR natively
// on gfx950 (unified file), and an asm-defined value cannot be rematerialized.

template<int R, bool DENSE>
__device__ __forceinline__ void run_loop(
    bf16x8 (&wall)[30], const __bf16* __restrict__ wsb,
    const __bf16* __restrict__ WLDS, __bf16* __restrict__ Zb, __bf16* __restrict__ CBb,
    float (&creg)[2][4], const float (&biasv)[2][4], float ybias,
    float* __restrict__ outp, int w, int lr, int lg, int l)
{
    constexpr int NS = 16 - R - 3;    // stream hc count: 9 (w<4) or 7
    const __bf16* wstr_base = wsb +
        (size_t)(64 + (w < 4 ? w * 9 : 36 + (w - 4) * 7)) * HC_ELEMS + l * 8;
    const __bf16* wlds_base = WLDS + (size_t)(w * 3) * HC_ELEMS + l * 8;

    for (int t = 0; t < SEQ; ++t) {
        __syncthreads();   // barrier 1: Z[cur] (h + x) complete

        const __bf16* Zc = Zb + (t & 1) * (16 * ZSTR);
        __bf16*       Zn = Zb + ((t + 1) & 1) * (16 * ZSTR);

        // anti-LICM: launder the stream pointer so loop-invariant loads
        // are not hoisted out of the t-loop (which would spill everything).
        const __bf16* wstr = wstr_base;
        asm volatile("" : "+v"(wstr));

        bf16x8 sb0[5], sb1[5];
#define LOADSTR(BUF, I) { _Pragma("unroll") \
        for (int c = 0; c < 5; ++c) BUF[c] = *(const bf16x8*)(wstr + (I) * HC_ELEMS + c * 512); }
        LOADSTR(sb0, 0)
        LOADSTR(sb1, 1)

        // A-fragments: lane holds Z[lr][k = ks*32 + lg*8 + e]
        bf16x8 a[10];
#pragma unroll
        for (int ks = 0; ks < 10; ++ks)
            a[ks] = *(const bf16x8*)(&Zc[lr * ZSTR + ks * 32 + lg * 8]);

        f32x4 acc[4];
        int scnt = 0;
#pragma unroll
        for (int idx = 0; idx < 16; ++idx) {
            const int p = idx >> 3, nt = (idx >> 1) & 3, h = idx & 1;
            const float bb = biasv[p][nt];
            f32x4 cc = (h == 0) ? f32x4{bb, bb, bb, bb} : acc[nt];

#define MFMA5(SRC) { _Pragma("unroll") \
            for (int c = 0; c < 5; ++c) \
                cc = __builtin_amdgcn_mfma_f32_16x16x32_bf16(a[h * 5 + c], SRC, cc, 0, 0, 0); }

            if (idx < R) {
                MFMA5(wall[idx * 5 + c])
            } else if (idx < R + 3) {
                bf16x8 ld[5];
#pragma unroll
                for (int c = 0; c < 5; ++c)
                    ld[c] = *(const bf16x8*)(wlds_base + (idx - R) * HC_ELEMS + c * 512);
                MFMA5(ld[c])
            } else {
                if (scnt & 1) {
                    MFMA5(sb1[c])
                    if (scnt + 2 < NS) LOADSTR(sb1, scnt + 2)
                } else {
                    MFMA5(sb0[c])
                    if (scnt + 2 < NS) LOADSTR(sb0, scnt + 2)
                }
                ++scnt;
            }
            acc[nt] = cc;

            if ((idx & 7) == 7) {
                // element-wise LSTM update for slice p
                const int jj = (2 * w + p) * 16 + lr;
#pragma unroll
                for (int r = 0; r < 4; ++r) {
                    const int m = lg * 4 + r;
                    const float ig = sigm(acc[0][r]);
                    const float fg = sigm(acc[1][r]);
                    const float gg = tanh_(acc[2][r]);
                    const float og = sigm(acc[3][r]);
                    const float cn = fg * creg[p][r] + ig * gg;
                    creg[p][r] = cn;
                    const float hn = og * tanh_(cn);
                    Zn[m * ZSTR + 64 + jj] = (__bf16)hn;
                    CBb[m * CSTR + jj]     = (__bf16)cn;
                }
            }
        }

        __syncthreads();   // barrier 2: CB ready

        if (DENSE) {
            // y_t = c_new @ W_dense^T + b_dense (waves 0..3, col f in [16w,16w+16))
            f32x4 ya = {ybias, ybias, ybias, ybias};
#pragma unroll
            for (int c = 0; c < 8; ++c) {
                bf16x8 acb = *(const bf16x8*)(&CBb[lr * CSTR + c * 32 + lg * 8]);
                ya = __builtin_amdgcn_mfma_f32_16x16x32_bf16(acb, wall[R * 5 + c], ya, 0, 0, 0);
            }
            const int f = w * 16 + lr;
#pragma unroll
            for (int r = 0; r < 4; ++r) {
                const int m = lg * 4 + r;
                outp[(size_t)m * (SEQ * FD) + t * FD + f] = ya[r];  // fp32 output
                Zn[m * ZSTR + f] = (__bf16)ya[r];                   // x for next step
            }
        }
    }
#undef MFMA5
#undef LOADSTR
}

__global__ __launch_bounds__(512) __attribute__((amdgpu_waves_per_eu(2, 2)))
void lstm_persist(
    const float* __restrict__ h0, const float* __restrict__ c0,
    const float* __restrict__ b_ih, const float* __restrict__ b_hh,
    const float* __restrict__ b_dense, const __bf16* __restrict__ wsb,
    float* __restrict__ out)
{
    __shared__ __align__(16) __bf16 WLDS[24 * HC_ELEMS];   // 122,880 B
    __shared__ __align__(16) __bf16 Zb[2 * 16 * ZSTR];     //  20,736 B
    __shared__ __align__(16) __bf16 CBb[16 * CSTR];        //   8,320 B

    const int tid = threadIdx.x;
    const int w   = tid >> 6;
    const int l   = tid & 63;
    const int lr  = l & 15;
    const int lg  = l >> 4;
    const int row0 = blockIdx.x * 16;
    const int R = (w < 4) ? 4 : 6;

    // ---- resident weights: gate chunks [0,5R); dense (w<4) [20,28) ----
    bf16x8 wall[30];
    if (w < 4) {
#pragma unroll
        for (int i = 0; i < 4; ++i)
#pragma unroll
            for (int c = 0; c < 5; ++c)
                wall[i * 5 + c] = *(const bf16x8*)(wsb + (size_t)hc_slot(w, i) * HC_ELEMS + c * 512 + l * 8);
#pragma unroll
        for (int c = 0; c < 8; ++c)   // dense chunks at [20, 28)
            wall[20 + c] = *(const bf16x8*)(wsb + WS_DENSE_ELEM + w * 4096 + c * 512 + l * 8);
        // pin the 28 live chunks into the AGPR half of the unified file
#pragma unroll
        for (int i = 0; i < 28; ++i) asm volatile("" : "+a"(wall[i]));
    } else {
#pragma unroll
        for (int i = 0; i < 6; ++i)
#pragma unroll
            for (int c = 0; c < 5; ++c)
                wall[i * 5 + c] = *(const bf16x8*)(wsb + (size_t)hc_slot(w, i) * HC_ELEMS + c * 512 + l * 8);
#pragma unroll
        for (int i = 0; i < 30; ++i) asm volatile("" : "+a"(wall[i]));
    }

    // ---- LDS-resident weights: each wave stages its 3 hc (one-time) ----
#pragma unroll
    for (int i = 0; i < 3; ++i)
#pragma unroll
        for (int c = 0; c < 5; ++c)
            *(bf16x8*)(WLDS + (size_t)(w * 3 + i) * HC_ELEMS + c * 512 + l * 8) =
                *(const bf16x8*)(wsb + (size_t)hc_slot(w, R + i) * HC_ELEMS + c * 512 + l * 8);

    // ---- biases, initial state ----
    float biasv[2][4];
    float creg[2][4];
#pragma unroll
    for (int p = 0; p < 2; ++p) {
        const int jj = (2 * w + p) * 16 + lr;
#pragma unroll
        for (int nt = 0; nt < 4; ++nt) {
            const int n = nt * 256 + jj;
            biasv[p][nt] = b_ih[n] + b_hh[n];
        }
#pragma unroll
        for (int r = 0; r < 4; ++r)
            creg[p][r] = c0[(size_t)(row0 + lg * 4 + r) * HD + jj];
    }
    float ybias = (w < 4) ? b_dense[w * 16 + lr] : 0.0f;

    // ---- stage h0 into Z0 h-part (512 threads x 8 elems) ----
    {
        const int e0 = tid * 8;
        const int m  = e0 >> 8;
        const int jj = e0 & 255;
        const float4 h1 = *(const float4*)(h0 + (size_t)(row0 + m) * HD + jj);
        const float4 h2 = *(const float4*)(h0 + (size_t)(row0 + m) * HD + jj + 4);
        __bf16* zp = &Zb[m * ZSTR + 64 + jj];
        zp[0] = (__bf16)h1.x; zp[1] = (__bf16)h1.y; zp[2] = (__bf16)h1.z; zp[3] = (__bf16)h1.w;
        zp[4] = (__bf16)h2.x; zp[5] = (__bf16)h2.y; zp[6] = (__bf16)h2.z; zp[7] = (__bf16)h2.w;
    }
    __syncthreads();

    // ---- x_0 = dense(h0) -> Z0 x-part ----
    if (w < 4) {
        f32x4 ya = {ybias, ybias, ybias, ybias};
#pragma unroll
        for (int c = 0; c < 8; ++c) {
            bf16x8 av = *(const bf16x8*)(&Zb[lr * ZSTR + 64 + c * 32 + lg * 8]);
            ya = __builtin_amdgcn_mfma_f32_16x16x32_bf16(av, wall[20 + c], ya, 0, 0, 0);
        }
#pragma unroll
        for (int r = 0; r < 4; ++r)
            Zb[(lg * 4 + r) * ZSTR + w * 16 + lr] = (__bf16)ya[r];
    }

    float* outp = out + (size_t)row0 * SEQ * FD;

    if (w < 4) run_loop<4, true >(wall, wsb, WLDS, Zb, CBb, creg, biasv, ybias, outp, w, lr, lg, l);
    else       run_loop<6, false>(wall, wsb, WLDS, Zb, CBb, creg, biasv, ybias, outp, w, lr, lg, l);
}

extern "C" void kernel_launch(void* const* d_in, const int* in_sizes, int n_in,
                              void* d_out, int out_size, void* d_ws, size_t ws_size,
                              hipStream_t stream) {
    (void)in_sizes; (void)n_in; (void)ws_size; (void)out_size;
    const float* h0      = (const float*)d_in[1];
    const float* c0      = (const float*)d_in[2];
    const float* W_ih    = (const float*)d_in[3];
    const float* W_hh    = (const float*)d_in[4];
    const float* b_ih    = (const float*)d_in[5];
    const float* b_hh    = (const float*)d_in[6];
    const float* W_dense = (const float*)d_in[7];
    const float* b_dense = (const float*)d_in[8];
    __bf16* wsb = (__bf16*)d_ws;    // uses 688,128 bytes of workspace

    prep_weights<<<132, 64, 0, stream>>>(W_ih, W_hh, W_dense, wsb);
    lstm_persist<<<128, 512, 0, stream>>>(h0, c0, b_ih, b_hh, b_dense, wsb, (float*)d_out);
}